// Round 1
// baseline (361.477 us; speedup 1.0000x reference)
//
#include <hip/hip_runtime.h>
#include <hip/hip_bf16.h>

typedef __bf16 bf16x8 __attribute__((ext_vector_type(8)));
typedef __bf16 bf16x4 __attribute__((ext_vector_type(4)));
typedef float  f32x4  __attribute__((ext_vector_type(4)));

#define DIM 1024
#define NHEAD 16
#define HD 64
#define BATCH 4
#define SEQ 2048
#define MROWS (BATCH * SEQ)        // 8192
#define NX (MROWS * DIM)           // 8388608
#define NQW (3 * DIM * DIM)        // 3145728
#define NPW (DIM * DIM)            // 1048576

// ---------------- fp32 -> bf16 convert (all three tensors, one launch) ----
__global__ void cvt_all(const float* __restrict__ x, const float* __restrict__ wq,
                        const float* __restrict__ wp, __bf16* __restrict__ xb,
                        __bf16* __restrict__ wqb, __bf16* __restrict__ wpb) {
    const int total = (NX + NQW + NPW) / 4;
    int stride = gridDim.x * blockDim.x;
    for (int c = blockIdx.x * blockDim.x + threadIdx.x; c < total; c += stride) {
        int i = c * 4;
        const float* src; __bf16* dst; int off;
        if (i < NX)            { src = x;  dst = xb;  off = i; }
        else if (i < NX + NQW) { src = wq; dst = wqb; off = i - NX; }
        else                   { src = wp; dst = wpb; off = i - NX - NQW; }
        float4 v = *(const float4*)&src[off];
        bf16x4 o = { (__bf16)v.x, (__bf16)v.y, (__bf16)v.z, (__bf16)v.w };
        *(bf16x4*)&dst[off] = o;
    }
}

// ---------------- GEMM1: qkv = x @ w_qkv.T, scatter to Q/K/V --------------
// C[m][n] = sum_k X[m][k] * W[n][k].  128x128 tile, 4 waves of 64x64.
__global__ __launch_bounds__(256) void gemm_qkv(
    const __bf16* __restrict__ X, const __bf16* __restrict__ W,
    __bf16* __restrict__ Qo, __bf16* __restrict__ Ko, __bf16* __restrict__ Vo) {
    __shared__ __align__(16) __bf16 As[128][72];
    __shared__ __align__(16) __bf16 Bs[128][72];
    const int m0 = blockIdx.y * 128, n0 = blockIdx.x * 128;
    const int tid = threadIdx.x;
    const int w = tid >> 6, lane = tid & 63;
    const int wm = w >> 1, wn = w & 1;
    const int lr = lane & 15, lg = lane >> 4;
    const int ldr = tid >> 3;          // 0..31
    const int ldc = (tid & 7) * 8;     // 0..56

    f32x4 acc[4][4];
    const f32x4 z = {0.f, 0.f, 0.f, 0.f};
#pragma unroll
    for (int i = 0; i < 4; ++i)
#pragma unroll
        for (int j = 0; j < 4; ++j) acc[i][j] = z;

    for (int kt = 0; kt < DIM; kt += 64) {
#pragma unroll
        for (int rr = 0; rr < 128; rr += 32) {
            *(bf16x8*)&As[ldr + rr][ldc] =
                *(const bf16x8*)&X[(size_t)(m0 + ldr + rr) * DIM + kt + ldc];
            *(bf16x8*)&Bs[ldr + rr][ldc] =
                *(const bf16x8*)&W[(size_t)(n0 + ldr + rr) * DIM + kt + ldc];
        }
        __syncthreads();
#pragma unroll
        for (int kk = 0; kk < 2; ++kk) {
            bf16x8 a[4], b[4];
#pragma unroll
            for (int i = 0; i < 4; ++i)
                a[i] = *(const bf16x8*)&As[wm * 64 + i * 16 + lr][kk * 32 + lg * 8];
#pragma unroll
            for (int j = 0; j < 4; ++j)
                b[j] = *(const bf16x8*)&Bs[wn * 64 + j * 16 + lr][kk * 32 + lg * 8];
#pragma unroll
            for (int i = 0; i < 4; ++i)
#pragma unroll
                for (int j = 0; j < 4; ++j)
                    acc[i][j] = __builtin_amdgcn_mfma_f32_16x16x32_bf16(a[i], b[j], acc[i][j], 0, 0, 0);
        }
        __syncthreads();
    }

    // epilogue: n -> (t, h, d); t uniform per block (128 | 1024)
    const int t = n0 >> 10;
    __bf16* dst = (t == 0) ? Qo : ((t == 1) ? Ko : Vo);
    const float sc = (t == 0) ? 0.125f : 1.0f;   // SCALE = hd^-0.5 = 1/8, exact
#pragma unroll
    for (int i = 0; i < 4; ++i) {
#pragma unroll
        for (int j = 0; j < 4; ++j) {
            int n = n0 + wn * 64 + j * 16 + lr;
            int rem = n & 1023, h = rem >> 6, d = rem & 63;
#pragma unroll
            for (int rr = 0; rr < 4; ++rr) {
                int m = m0 + wm * 64 + i * 16 + lg * 4 + rr;
                int b = m >> 11, pos = m & 2047;
                dst[(((size_t)b * NHEAD + h) * SEQ + pos) * HD + d] =
                    (__bf16)(acc[i][j][rr] * sc);
            }
        }
    }
}

// ---------------- flash attention ------------------------------------------
// grid (16, 64): y = bh, x = q-tile of 128 rows; 4 waves x 32 q-rows.
__global__ __launch_bounds__(256) void flash_attn(
    const __bf16* __restrict__ Q, const __bf16* __restrict__ K,
    const __bf16* __restrict__ V, __bf16* __restrict__ AO) {
    __shared__ __align__(16) __bf16 P_lds[4][32][72];
    const int bh = blockIdx.y;
    const int w = threadIdx.x >> 6, lane = threadIdx.x & 63;
    const int lr = lane & 15, lg = lane >> 4;
    const int qbase = blockIdx.x * 128 + w * 32;
    const size_t kv = (size_t)bh * SEQ * HD;

    bf16x8 qf[2][2];
#pragma unroll
    for (int i = 0; i < 2; ++i)
#pragma unroll
        for (int dk = 0; dk < 2; ++dk)
            qf[i][dk] = *(const bf16x8*)&Q[kv + (size_t)(qbase + i * 16 + lr) * HD + dk * 32 + lg * 8];

    float m_r[2][4], l_r[2][4];
    f32x4 o_acc[2][4];
    const f32x4 z = {0.f, 0.f, 0.f, 0.f};
#pragma unroll
    for (int i = 0; i < 2; ++i) {
#pragma unroll
        for (int rr = 0; rr < 4; ++rr) { m_r[i][rr] = -1e30f; l_r[i][rr] = 0.f; }
#pragma unroll
        for (int dj = 0; dj < 4; ++dj) o_acc[i][dj] = z;
    }

    for (int kt = 0; kt < SEQ / 64; ++kt) {
        const int k0 = kt * 64;
        f32x4 s[2][4];
#pragma unroll
        for (int i = 0; i < 2; ++i)
#pragma unroll
            for (int j = 0; j < 4; ++j) s[i][j] = z;
#pragma unroll
        for (int dk = 0; dk < 2; ++dk) {
            bf16x8 kf[4];
#pragma unroll
            for (int j = 0; j < 4; ++j)
                kf[j] = *(const bf16x8*)&K[kv + (size_t)(k0 + j * 16 + lr) * HD + dk * 32 + lg * 8];
#pragma unroll
            for (int i = 0; i < 2; ++i)
#pragma unroll
                for (int j = 0; j < 4; ++j)
                    s[i][j] = __builtin_amdgcn_mfma_f32_16x16x32_bf16(qf[i][dk], kf[j], s[i][j], 0, 0, 0);
        }
        // online softmax (wave-parallel: 16-lane group reduce)
#pragma unroll
        for (int i = 0; i < 2; ++i) {
#pragma unroll
            for (int rr = 0; rr < 4; ++rr) {
                float mx = fmaxf(fmaxf(s[i][0][rr], s[i][1][rr]),
                                 fmaxf(s[i][2][rr], s[i][3][rr]));
                mx = fmaxf(mx, __shfl_xor(mx, 1));
                mx = fmaxf(mx, __shfl_xor(mx, 2));
                mx = fmaxf(mx, __shfl_xor(mx, 4));
                mx = fmaxf(mx, __shfl_xor(mx, 8));
                float mnew = fmaxf(m_r[i][rr], mx);
                float alpha = __expf(m_r[i][rr] - mnew);
                m_r[i][rr] = mnew;
                float rs = 0.f;
#pragma unroll
                for (int j = 0; j < 4; ++j) {
                    float p = __expf(s[i][j][rr] - mnew);
                    s[i][j][rr] = p;
                    rs += p;
                }
                rs += __shfl_xor(rs, 1);
                rs += __shfl_xor(rs, 2);
                rs += __shfl_xor(rs, 4);
                rs += __shfl_xor(rs, 8);
                l_r[i][rr] = l_r[i][rr] * alpha + rs;
#pragma unroll
                for (int dj = 0; dj < 4; ++dj) o_acc[i][dj][rr] *= alpha;
            }
        }
        __syncthreads();   // WAR: previous PV reads of P_lds done before rewrite
        // P (D-layout) -> LDS as bf16, per-wave private region
#pragma unroll
        for (int i = 0; i < 2; ++i)
#pragma unroll
            for (int j = 0; j < 4; ++j)
#pragma unroll
                for (int rr = 0; rr < 4; ++rr)
                    P_lds[w][i * 16 + lg * 4 + rr][j * 16 + lr] = (__bf16)s[i][j][rr];
        __syncthreads();   // RAW: writes visible before A-frag reads
        // PV: O += P @ V
#pragma unroll
        for (int kk = 0; kk < 2; ++kk) {
            bf16x8 pf[2];
#pragma unroll
            for (int i = 0; i < 2; ++i)
                pf[i] = *(const bf16x8*)&P_lds[w][i * 16 + lr][kk * 32 + lg * 8];
#pragma unroll
            for (int dj = 0; dj < 4; ++dj) {
                bf16x8 vf;
#pragma unroll
                for (int jj = 0; jj < 8; ++jj)
                    vf[jj] = V[kv + (size_t)(k0 + kk * 32 + lg * 8 + jj) * HD + dj * 16 + lr];
#pragma unroll
                for (int i = 0; i < 2; ++i)
                    o_acc[i][dj] = __builtin_amdgcn_mfma_f32_16x16x32_bf16(pf[i], vf, o_acc[i][dj], 0, 0, 0);
            }
        }
    }
    // epilogue: AO[b*2048+q][h*64+d] bf16
    const int b = bh >> 4, h = bh & 15;
#pragma unroll
    for (int i = 0; i < 2; ++i) {
#pragma unroll
        for (int rr = 0; rr < 4; ++rr) {
            float inv = 1.f / l_r[i][rr];
            int qpos = qbase + i * 16 + lg * 4 + rr;
#pragma unroll
            for (int dj = 0; dj < 4; ++dj)
                AO[((size_t)b * SEQ + qpos) * DIM + h * HD + dj * 16 + lr] =
                    (__bf16)(o_acc[i][dj][rr] * inv);
        }
    }
}

// ---------------- GEMM2: out = AO @ w_proj.T + b_proj (fp32 out) ----------
__global__ __launch_bounds__(256) void gemm_proj(
    const __bf16* __restrict__ A, const __bf16* __restrict__ W,
    const float* __restrict__ bias, float* __restrict__ out) {
    __shared__ __align__(16) __bf16 As[128][72];
    __shared__ __align__(16) __bf16 Bs[128][72];
    const int m0 = blockIdx.y * 128, n0 = blockIdx.x * 128;
    const int tid = threadIdx.x;
    const int w = tid >> 6, lane = tid & 63;
    const int wm = w >> 1, wn = w & 1;
    const int lr = lane & 15, lg = lane >> 4;
    const int ldr = tid >> 3;
    const int ldc = (tid & 7) * 8;

    f32x4 acc[4][4];
    const f32x4 z = {0.f, 0.f, 0.f, 0.f};
#pragma unroll
    for (int i = 0; i < 4; ++i)
#pragma unroll
        for (int j = 0; j < 4; ++j) acc[i][j] = z;

    for (int kt = 0; kt < DIM; kt += 64) {
#pragma unroll
        for (int rr = 0; rr < 128; rr += 32) {
            *(bf16x8*)&As[ldr + rr][ldc] =
                *(const bf16x8*)&A[(size_t)(m0 + ldr + rr) * DIM + kt + ldc];
            *(bf16x8*)&Bs[ldr + rr][ldc] =
                *(const bf16x8*)&W[(size_t)(n0 + ldr + rr) * DIM + kt + ldc];
        }
        __syncthreads();
#pragma unroll
        for (int kk = 0; kk < 2; ++kk) {
            bf16x8 a[4], b[4];
#pragma unroll
            for (int i = 0; i < 4; ++i)
                a[i] = *(const bf16x8*)&As[wm * 64 + i * 16 + lr][kk * 32 + lg * 8];
#pragma unroll
            for (int j = 0; j < 4; ++j)
                b[j] = *(const bf16x8*)&Bs[wn * 64 + j * 16 + lr][kk * 32 + lg * 8];
#pragma unroll
            for (int i = 0; i < 4; ++i)
#pragma unroll
                for (int j = 0; j < 4; ++j)
                    acc[i][j] = __builtin_amdgcn_mfma_f32_16x16x32_bf16(a[i], b[j], acc[i][j], 0, 0, 0);
        }
        __syncthreads();
    }

#pragma unroll
    for (int i = 0; i < 4; ++i) {
#pragma unroll
        for (int j = 0; j < 4; ++j) {
            int n = n0 + wn * 64 + j * 16 + lr;
            float bv = bias[n];
#pragma unroll
            for (int rr = 0; rr < 4; ++rr) {
                int m = m0 + wm * 64 + i * 16 + lg * 4 + rr;
                out[(size_t)m * DIM + n] = acc[i][j][rr] + bv;
            }
        }
    }
}

extern "C" void kernel_launch(void* const* d_in, const int* in_sizes, int n_in,
                              void* d_out, int out_size, void* d_ws, size_t ws_size,
                              hipStream_t stream) {
    const float* x    = (const float*)d_in[0];
    const float* wqkv = (const float*)d_in[1];
    const float* wproj= (const float*)d_in[2];
    const float* bproj= (const float*)d_in[3];
    float* out = (float*)d_out;

    __bf16* xb  = (__bf16*)d_ws;            // 8388608  (reused as AO later)
    __bf16* wqb = xb + NX;                  // 3145728
    __bf16* wpb = wqb + NQW;                // 1048576
    __bf16* Qb  = wpb + NPW;                // 8388608
    __bf16* Kb  = Qb + (size_t)NX;
    __bf16* Vb  = Kb + (size_t)NX;
    __bf16* AO  = xb;                       // alias: xb dead after gemm_qkv

    cvt_all<<<2048, 256, 0, stream>>>(x, wqkv, wproj, xb, wqb, wpb);
    gemm_qkv<<<dim3(24, 64), 256, 0, stream>>>(xb, wqb, Qb, Kb, Vb);
    flash_attn<<<dim3(16, 64), 256, 0, stream>>>(Qb, Kb, Vb, AO);
    gemm_proj<<<dim3(8, 64), 256, 0, stream>>>(AO, wpb, bproj, out);
}